// Round 6
// baseline (42757.632 us; speedup 1.0000x reference)
//
#include <hip/hip_runtime.h>
#include <hip/hip_bf16.h>
#include <stdint.h>

// Neural ODE (RK4, 32 steps) over a 5-layer MLP, B=32768, VAR_DIM=50 (pad 64).
// bf16 MFMA GEMMs (16x16x32), fp32 accum, fp32 state y.
// concat(h,t) @ W == h @ W[:K] + (b + t*W[K]) -> time column folded into bias.
// r5: cross-phase fragment pipelining in gemm256 — every ds_read batch issues
//     one full phase before its consuming MFMA (incl. cross-tile prefetch at
//     phase 3 under the vmcnt(4)+barrier guarantee). Counted lgkm waits.

typedef __bf16 bf16_t;
typedef bf16_t bf16x8 __attribute__((ext_vector_type(8)));
typedef float  f32x4  __attribute__((ext_vector_type(4)));

#define DEVI static __device__ __forceinline__

DEVI void gload_lds16(const bf16_t* gsrc, bf16_t* ldst) {
  __builtin_amdgcn_global_load_lds(
      (const __attribute__((address_space(1))) uint32_t*)gsrc,
      (__attribute__((address_space(3))) uint32_t*)ldst,
      16, 0, 0);
}

// ---------------------------------------------------------------------------
// 256x256 tile, BK=64, 8 waves (2Mx4N), double-buffered LDS, 8-phase schedule
// with 1-phase-ahead fragment reads.
// DS ledger per tile T (per wave, in-order retire):
//   p3(T-1): issue af0+bfr[0..3] for T (12)        [cross, after vmcnt+bar]
//   p0: issue bfr[4..7] (4)   -> wait lgkm(4)  = cross done     ; MFMA(0,0)
//   p1: issue af1 (8)         -> wait lgkm(8)  = nh1 done       ; MFMA(0,1)
//   p2: (none)                -> wait lgkm(0)  = af1 done       ; MFMA(1,0)
//   p3: vmcnt(4)+bar; issue next cross (12); no wait            ; MFMA(1,1)
// Staging writes land >=1 trailing barrier after their region's last
// reader drained (checked region-by-region).
// ---------------------------------------------------------------------------
template<int K>
__global__ __launch_bounds__(512, 1) void gemm256(
    const bf16_t* __restrict__ A,     // M x K row-major
    const bf16_t* __restrict__ BT,    // N x K row-major (pre-transposed W)
    const float* __restrict__ bias,
    const float* __restrict__ wtime,
    float t,
    bf16_t* __restrict__ C, int ldc,
    int M, int N)
{
  constexpr int NT = K / 64;          // K-tiles
  static_assert(NT >= 3, "pipeline needs >=3 K-tiles");

  __shared__ __align__(16) bf16_t As[2][256][64];
  __shared__ __align__(16) bf16_t Bs[2][256][64];

  const int tid  = threadIdx.x;
  const int wave = tid >> 6;
  const int lane = tid & 63;
  const int wr = wave >> 2;           // 0..1 -> 128-row half
  const int wc = wave & 3;            // 0..3 -> 64-col strip

  // T1: XCD-aware bijective swizzle (gridDim.x % 8 == 0 by construction)
  int wg = blockIdx.x;
  {
    const int cpx = gridDim.x >> 3;
    wg = (wg & 7) * cpx + (wg >> 3);
  }
  const int nbn = N >> 8;
  const int bm = (wg / nbn) << 8;
  const int bn = (wg % nbn) << 8;

  // staging: dest row r = [buf*256 + h*128 +] wave*8 + (lane>>3)
  //   r&4 = lane&32-bit, r&8 = wave&1.  Pre-swizzled SOURCE col.
  const int srow = lane >> 3;
  const int scol = ((lane & 7) << 3) ^ ((lane & 32) >> 1) ^ ((wave & 1) << 5);
  const bf16_t* aS = A  + (size_t)(bm + wave * 8 + srow) * K + scol;
  const bf16_t* bS = BT + (size_t)(bn + wave * 8 + srow) * K + scol;
  bf16_t* aD = &As[0][0][0] + wave * 8 * 64;   // wave-uniform LDS base
  bf16_t* bD = &Bs[0][0][0] + wave * 8 * 64;

  auto stageHalf = [&](int kt, int isB, int h) {
    const int buf = kt & 1;
    const bf16_t* src = (isB ? bS : aS) + (size_t)(h * 128) * K + kt * 64;
    bf16_t*       dst = (isB ? bD : aD) + (buf * 256 + h * 128) * 64;
    gload_lds16(src,                  dst);
    gload_lds16(src + (size_t)64 * K, dst + 64 * 64);
  };

  const int fr = lane & 15;
  const int fq = lane >> 4;
  const int rsw = ((fr & 4) << 3) ^ ((fr & 8) << 3);   // byte-XOR from row bits

  bf16x8 af0[8], af1[8];   // A frags, mh=0 / mh=1 (ping-pong across phases)
  bf16x8 bfr[8];           // B frags [nh*4 + n*2 + kk], whole tile
  f32x4  acc[8][4] = {};

  auto lda_into = [&](bf16x8 (&dst)[8], int buf, int mh) {
    const char* base = (const char*)&As[buf][0][0];
#pragma unroll
    for (int m = 0; m < 4; ++m)
#pragma unroll
      for (int kk = 0; kk < 2; ++kk) {
        int r  = wr * 128 + (mh * 4 + m) * 16 + fr;
        int cb = (kk * 64 + fq * 16) ^ rsw;
        dst[m * 2 + kk] = *(const bf16x8*)(base + r * 128 + cb);
      }
  };
  auto ldb_half = [&](int buf, int nh) {   // fills bfr[nh*4 .. nh*4+3]
    const char* base = (const char*)&Bs[buf][0][0];
#pragma unroll
    for (int n = 0; n < 2; ++n)
#pragma unroll
      for (int kk = 0; kk < 2; ++kk) {
        int r  = wc * 64 + (nh * 2 + n) * 16 + fr;
        int cb = (kk * 64 + fq * 16) ^ rsw;
        bfr[nh * 4 + n * 2 + kk] = *(const bf16x8*)(base + r * 128 + cb);
      }
  };
  auto mma_quad = [&](bf16x8 (&a)[8], int mh, int nh) {
    __builtin_amdgcn_s_setprio(1);
#pragma unroll
    for (int m = 0; m < 4; ++m)
#pragma unroll
      for (int n = 0; n < 2; ++n)
#pragma unroll
        for (int kk = 0; kk < 2; ++kk)
          acc[mh * 4 + m][nh * 2 + n] = __builtin_amdgcn_mfma_f32_16x16x32_bf16(
              a[m * 2 + kk], bfr[nh * 4 + n * 2 + kk],
              acc[mh * 4 + m][nh * 2 + n], 0, 0, 0);
    __builtin_amdgcn_s_setprio(0);
  };

  // prologue: tile0 full + tile1 {Bh0, Ah0}; then tile-0 cross-frag reads
  stageHalf(0, 0, 0); stageHalf(0, 1, 0);
  stageHalf(0, 0, 1); stageHalf(0, 1, 1);
  stageHalf(1, 1, 0); stageHalf(1, 0, 0);
  asm volatile("s_waitcnt vmcnt(4)" ::: "memory");   // tile0 resident
  __builtin_amdgcn_s_barrier();
  lda_into(af0, 0, 0);
  ldb_half(0, 0);

  for (int t2 = 0; t2 < NT; ++t2) {
    const int buf = t2 & 1;
    // phase 0: MFMA (0,0) on af0+bfr[0..3] (issued prev p3); prefetch nh1
    ldb_half(buf, 1);                                 // 4 reads
    if (t2 + 1 < NT) stageHalf(t2 + 1, 0, 1);         // Ah1(T+1) -> other buf
    __builtin_amdgcn_s_barrier();
    asm volatile("s_waitcnt lgkmcnt(4)" ::: "memory");  // cross-12 done
    mma_quad(af0, 0, 0);
    __builtin_amdgcn_s_barrier();
    // phase 1: MFMA (0,1) on af0+bfr[4..7] (issued p0); prefetch af1
    lda_into(af1, buf, 1);                            // 8 reads
    if (t2 + 1 < NT) stageHalf(t2 + 1, 1, 1);         // Bh1(T+1) -> other buf
    __builtin_amdgcn_s_barrier();
    asm volatile("s_waitcnt lgkmcnt(8)" ::: "memory");  // nh1 done
    mma_quad(af0, 0, 1);
    __builtin_amdgcn_s_barrier();
    // phase 2: MFMA (1,0) on af1 (issued p1)+bfr[0..3]
    if (t2 + 2 < NT) stageHalf(t2 + 2, 1, 0);         // Bh0(T+2) -> this buf
    __builtin_amdgcn_s_barrier();
    asm volatile("s_waitcnt lgkmcnt(0)" ::: "memory");  // af1 done
    mma_quad(af1, 1, 0);
    __builtin_amdgcn_s_barrier();
    // phase 3: MFMA (1,1) on af1+bfr[4..7] (all drained); cross-prefetch T+1
    if (t2 + 2 < NT) {
      stageHalf(t2 + 2, 0, 0);                        // Ah0(T+2) -> this buf
      asm volatile("s_waitcnt vmcnt(4)" ::: "memory");  // T+1 fully resident
    } else {
      asm volatile("s_waitcnt vmcnt(0)" ::: "memory");
    }
    __builtin_amdgcn_s_barrier();
    if (t2 + 1 < NT) {
      lda_into(af0, buf ^ 1, 0);                      // 8 reads, next tile
      ldb_half(buf ^ 1, 0);                           // 4 reads, next tile
    }
    mma_quad(af1, 1, 1);
    __builtin_amdgcn_s_barrier();
  }

  // epilogue: bias(t) + ReLU, bf16 out
#pragma unroll
  for (int n = 0; n < 4; ++n) {
    const int gcol = bn + wc * 64 + n * 16 + fr;
    const float bv = bias[gcol] + t * wtime[gcol];
#pragma unroll
    for (int m = 0; m < 8; ++m) {
      const int grow0 = bm + wr * 128 + m * 16 + (fq << 2);
#pragma unroll
      for (int r = 0; r < 4; ++r) {
        float v = acc[m][n][r] + bv;
        v = v > 0.0f ? v : 0.0f;
        C[(size_t)(grow0 + r) * ldc + gcol] = (bf16_t)v;
      }
    }
  }
}

// ---------------------------------------------------------------------------
// 128^2 kernel for layer 0 (K=64), full bank-spread swizzle.
// ---------------------------------------------------------------------------
template<int BM, int BN, int BK, int WROWS, int WCOLS, bool RELU, bool OUT_BF16>
__global__ __launch_bounds__(256) void gemm_bt(
    const bf16_t* __restrict__ A, int lda,
    const bf16_t* __restrict__ BT,
    const float* __restrict__ bias,
    const float* __restrict__ wtime,
    float t,
    void* __restrict__ Cv, int ldc,
    int M, int K)
{
  static_assert(BK == 64, "swizzle assumes BK=64");
  constexpr int MR  = BM / WROWS / 16;
  constexpr int NR  = BN / WCOLS / 16;
  constexpr int TPR = BK / 8;        // 8
  constexpr int RPW = 64 / TPR;      // 8
  constexpr int RPL = 4 * RPW;       // 32
  static_assert(BM % RPL == 0 && BN % RPL == 0, "tile staging mismatch");

  __shared__ bf16_t As[BM][BK];
  __shared__ bf16_t Bs[BN][BK];

  const int tid  = threadIdx.x;
  const int wave = tid >> 6;
  const int lane = tid & 63;
  const int wr = wave / WCOLS;
  const int wc = wave % WCOLS;
  const int bm = blockIdx.x * BM;
  const int bn = blockIdx.y * BN;
  const int lrow = lane >> 3;
  const int lcol = (((lane & 7) << 3) ^ ((lane & 32) >> 1) ^ ((wave & 1) << 5));

  const int fr = lane & 15;
  const int fq = lane >> 4;
  const int esw = ((fr & 4) << 2) ^ ((fr & 8) << 2);  // element-XOR from row bits

  f32x4 acc[MR][NR] = {};

  for (int k0 = 0; k0 < K; k0 += BK) {
#pragma unroll
    for (int i = 0; i < BM / RPL; ++i) {
      const int rb = i * RPL + wave * RPW;
      gload_lds16(&A[(size_t)(bm + rb + lrow) * lda + k0 + lcol], &As[rb][0]);
    }
#pragma unroll
    for (int i = 0; i < BN / RPL; ++i) {
      const int rb = i * RPL + wave * RPW;
      gload_lds16(&BT[(size_t)(bn + rb + lrow) * K + k0 + lcol], &Bs[rb][0]);
    }
    __syncthreads();
#pragma unroll
    for (int kk = 0; kk < BK / 32; ++kk) {
      bf16x8 af[MR], bfr[NR];
      const int ecol = (kk * 32 + fq * 8) ^ esw;
#pragma unroll
      for (int m = 0; m < MR; ++m)
        af[m] = *(const bf16x8*)&As[wr * (BM / WROWS) + m * 16 + fr][ecol];
#pragma unroll
      for (int n = 0; n < NR; ++n)
        bfr[n] = *(const bf16x8*)&Bs[wc * (BN / WCOLS) + n * 16 + fr][ecol];
#pragma unroll
      for (int m = 0; m < MR; ++m)
#pragma unroll
        for (int n = 0; n < NR; ++n)
          acc[m][n] = __builtin_amdgcn_mfma_f32_16x16x32_bf16(
              af[m], bfr[n], acc[m][n], 0, 0, 0);
    }
    __syncthreads();
  }

#pragma unroll
  for (int n = 0; n < NR; ++n) {
    const int gcol = bn + wc * (BN / WCOLS) + n * 16 + fr;
    const float bv = bias[gcol] + t * wtime[gcol];
#pragma unroll
    for (int m = 0; m < MR; ++m) {
      const int grow0 = bm + wr * (BM / WROWS) + m * 16 + (fq << 2);
#pragma unroll
      for (int r = 0; r < 4; ++r) {
        float v = acc[m][n][r] + bv;
        if (RELU) v = v > 0.0f ? v : 0.0f;
        if constexpr (OUT_BF16)
          ((bf16_t*)Cv)[(size_t)(grow0 + r) * ldc + gcol] = (bf16_t)v;
        else
          ((float*)Cv)[(size_t)(grow0 + r) * ldc + gcol] = v;
      }
    }
  }
}

// ---------------------------------------------------------------------------
// Layer 4 (N=64, K=1024) with RK4 combine fused into the epilogue.
// BM=64, BN=64, 4 waves (2x2) -> 512 blocks = 2 blocks/CU.  Swizzled LDS.
// ---------------------------------------------------------------------------
__global__ __launch_bounds__(256) void gemm_l4_rk4(
    const bf16_t* __restrict__ A, int lda,
    const bf16_t* __restrict__ BT,
    const float* __restrict__ bias,
    const float* __restrict__ wtime,
    float t,
    float* __restrict__ y, float* __restrict__ accb,
    bf16_t* __restrict__ ybf,
    float ca, float cs, int mode,
    int M, int K)
{
  constexpr int BM = 64, BN = 64, BK = 64;
  constexpr int MR = 2, NR = 2;

  __shared__ bf16_t As[BM][BK];
  __shared__ bf16_t Bs[BN][BK];

  const int tid  = threadIdx.x;
  const int wave = tid >> 6;
  const int lane = tid & 63;
  const int wr = wave >> 1;
  const int wc = wave & 1;
  const int bm = blockIdx.x * BM;
  const int lrow = lane >> 3;
  const int lcol = (((lane & 7) << 3) ^ ((lane & 32) >> 1) ^ ((wave & 1) << 5));

  const int fr = lane & 15;
  const int fq = lane >> 4;
  const int esw = ((fr & 4) << 2) ^ ((fr & 8) << 2);

  f32x4 acc[MR][NR] = {};

  for (int k0 = 0; k0 < K; k0 += BK) {
#pragma unroll
    for (int i = 0; i < 2; ++i) {
      const int rb = i * 32 + wave * 8;
      gload_lds16(&A[(size_t)(bm + rb + lrow) * lda + k0 + lcol], &As[rb][0]);
    }
#pragma unroll
    for (int i = 0; i < 2; ++i) {
      const int rb = i * 32 + wave * 8;
      gload_lds16(&BT[(size_t)(rb + lrow) * K + k0 + lcol], &Bs[rb][0]);
    }
    __syncthreads();
#pragma unroll
    for (int kk = 0; kk < 2; ++kk) {
      bf16x8 af[MR], bfr[NR];
      const int ecol = (kk * 32 + fq * 8) ^ esw;
#pragma unroll
      for (int m = 0; m < MR; ++m)
        af[m] = *(const bf16x8*)&As[wr * 32 + m * 16 + fr][ecol];
#pragma unroll
      for (int n = 0; n < NR; ++n)
        bfr[n] = *(const bf16x8*)&Bs[wc * 32 + n * 16 + fr][ecol];
#pragma unroll
      for (int m = 0; m < MR; ++m)
#pragma unroll
        for (int n = 0; n < NR; ++n)
          acc[m][n] = __builtin_amdgcn_mfma_f32_16x16x32_bf16(
              af[m], bfr[n], acc[m][n], 0, 0, 0);
    }
    __syncthreads();
  }

#pragma unroll
  for (int n = 0; n < NR; ++n) {
    const int gcol = wc * 32 + n * 16 + fr;
    const float bv = bias[gcol] + t * wtime[gcol];
#pragma unroll
    for (int m = 0; m < MR; ++m) {
      const int grow0 = bm + wr * 32 + m * 16 + (fq << 2);
#pragma unroll
      for (int r = 0; r < 4; ++r) {
        const float kv = acc[m][n][r] + bv;
        const size_t o = (size_t)(grow0 + r) * 64 + gcol;
        if (mode == 0) {
          accb[o] = kv;
          ybf[o] = (bf16_t)(y[o] + cs * kv);
        } else if (mode == 1) {
          accb[o] += ca * kv;
          ybf[o] = (bf16_t)(y[o] + cs * kv);
        } else {
          const float ny = y[o] + cs * (accb[o] + kv);
          y[o] = ny;
          ybf[o] = (bf16_t)ny;
        }
      }
    }
  }
}

// ---------------------------------------------------------------------------
__global__ void prep_weight(const float* __restrict__ W, const float* __restrict__ b,
                            bf16_t* __restrict__ WT, float* __restrict__ bias,
                            float* __restrict__ wtime,
                            int K, int N, int Kpad, int Npad)
{
  int idx = blockIdx.x * 256 + threadIdx.x;
  int total = Npad * Kpad;
  if (idx < total) {
    int n = idx / Kpad, k = idx % Kpad;
    float v = (n < N && k < K) ? W[(size_t)k * N + n] : 0.0f;
    WT[idx] = (bf16_t)v;
  }
  if (idx < Npad) {
    bias[idx]  = (idx < N) ? b[idx] : 0.0f;
    wtime[idx] = (idx < N) ? W[(size_t)K * N + idx] : 0.0f;
  }
}

__global__ void init_y(const float* __restrict__ x, float* __restrict__ y,
                       bf16_t* __restrict__ ybf, int M)
{
  int i = blockIdx.x * 256 + threadIdx.x;
  if (i < M * 64) {
    int m = i >> 6, c = i & 63;
    float v = (c < 2) ? x[m * 2 + c] : 0.0f;
    y[i] = v;
    ybf[i] = (bf16_t)v;
  }
}

__global__ void extract_out(const float* __restrict__ y, float* __restrict__ out, int M)
{
  int i = blockIdx.x * 256 + threadIdx.x;
  if (i < M * 3) {
    int m = i / 3, c = i % 3;
    out[i] = y[(size_t)m * 64 + c];
  }
}

extern "C" void kernel_launch(void* const* d_in, const int* in_sizes, int n_in,
                              void* d_out, int out_size, void* d_ws, size_t ws_size,
                              hipStream_t stream)
{
  (void)in_sizes; (void)n_in; (void)out_size; (void)ws_size;
  const int M = 32768;

  const float* x = (const float*)d_in[0];
  const float* Wp[5]; const float* bp[5];
  for (int i = 0; i < 5; ++i) {
    Wp[i] = (const float*)d_in[1 + 2 * i];
    bp[i] = (const float*)d_in[2 + 2 * i];
  }

  char* ws = (char*)d_ws; size_t off = 0;
  auto alloc = [&](size_t bytes) -> char* {
    char* p = ws + off; off += (bytes + 255) & ~(size_t)255; return p;
  };

  bf16_t* WT[5];
  WT[0] = (bf16_t*)alloc((size_t)1024 * 64 * 2);
  WT[1] = (bf16_t*)alloc((size_t)1024 * 1024 * 2);
  WT[2] = (bf16_t*)alloc((size_t)1024 * 1024 * 2);
  WT[3] = (bf16_t*)alloc((size_t)1024 * 1024 * 2);
  WT[4] = (bf16_t*)alloc((size_t)64 * 1024 * 2);
  float* bias[5]; float* wtm[5];
  for (int i = 0; i < 5; ++i) {
    int Np = (i == 4) ? 64 : 1024;
    bias[i] = (float*)alloc((size_t)Np * 4);
    wtm[i]  = (float*)alloc((size_t)Np * 4);
  }
  float*  y    = (float*)alloc((size_t)M * 64 * 4);
  float*  accb = (float*)alloc((size_t)M * 64 * 4);
  bf16_t* ybf  = (bf16_t*)alloc((size_t)M * 64 * 2);
  bf16_t* act0 = (bf16_t*)alloc((size_t)M * 1024 * 2);
  bf16_t* act1 = (bf16_t*)alloc((size_t)M * 1024 * 2);

  const int Kd[5]  = {50, 1024, 1024, 1024, 1024};
  const int Nd[5]  = {1024, 1024, 1024, 1024, 50};
  const int Kpd[5] = {64, 1024, 1024, 1024, 1024};
  const int Npd[5] = {1024, 1024, 1024, 1024, 64};
  for (int i = 0; i < 5; ++i) {
    int tot = Npd[i] * Kpd[i];
    prep_weight<<<dim3((tot + 255) / 256), 256, 0, stream>>>(
        Wp[i], bp[i], WT[i], bias[i], wtm[i], Kd[i], Nd[i], Kpd[i], Npd[i]);
  }

  init_y<<<dim3((M * 64 + 255) / 256), 256, 0, stream>>>(x, y, ybf, M);

  const float dtv = 1.0f / 32.0f;
  dim3 gL0(M / 128, 1024 / 128);        // 2048 blocks
  dim3 g256(M / 256 * (1024 / 256));    // 512 blocks, %8 == 0
  dim3 gL4(M / 64);                     // 512 blocks = 2/CU

  auto run_net = [&](float t, float ca, float cs, int mode) {
    gemm_bt<128,128,64,2,2,true,true><<<gL0, 256, 0, stream>>>(
        ybf, 64, WT[0], bias[0], wtm[0], t, act0, 1024, M, 64);
    gemm256<1024><<<g256, 512, 0, stream>>>(
        act0, WT[1], bias[1], wtm[1], t, act1, 1024, M, 1024);
    gemm256<1024><<<g256, 512, 0, stream>>>(
        act1, WT[2], bias[2], wtm[2], t, act0, 1024, M, 1024);
    gemm256<1024><<<g256, 512, 0, stream>>>(
        act0, WT[3], bias[3], wtm[3], t, act1, 1024, M, 1024);
    gemm_l4_rk4<<<gL4, 256, 0, stream>>>(
        act1, 1024, WT[4], bias[4], wtm[4], t,
        y, accb, ybf, ca, cs, mode, M, 1024);
  };

  for (int i = 0; i < 32; ++i) {
    const float t0 = i * dtv;
    const float tm = t0 + 0.5f * dtv;
    const float t1 = t0 + dtv;
    run_net(t0, 0.0f, 0.5f * dtv, 0);   // k1
    run_net(tm, 2.0f, 0.5f * dtv, 1);   // k2
    run_net(tm, 2.0f, dtv,        1);   // k3
    run_net(t1, 0.0f, dtv / 6.0f, 2);   // k4
  }

  extract_out<<<dim3((M * 3 + 255) / 256), 256, 0, stream>>>(y, (float*)d_out, M);
}

// Round 7
// 39333.371 us; speedup vs baseline: 1.0871x; 1.0871x over previous
//
#include <hip/hip_runtime.h>
#include <hip/hip_bf16.h>
#include <stdint.h>

// Neural ODE (RK4, 32 steps) over a 5-layer MLP, B=32768, VAR_DIM=50 (pad 64).
// bf16 MFMA GEMMs (16x16x32), fp32 accum, fp32 state y.
// concat(h,t) @ W == h @ W[:K] + (b + t*W[K]) -> time column folded into bias.
// r6: r4 structure, minus all explicit asm lgkmcnt waits in gemm256 —
//     the blanket lgkmcnt(0) drained all 8 waves' reads before any MFMA
//     (serializing LDS and matrix pipes); the compiler's automatic
//     fine-grained per-MFMA lgkm waits allow overlap. Barriers + counted
//     vmcnt ledger unchanged (hazard analysis identical to r4).

typedef __bf16 bf16_t;
typedef bf16_t bf16x8 __attribute__((ext_vector_type(8)));
typedef float  f32x4  __attribute__((ext_vector_type(4)));

#define DEVI static __device__ __forceinline__

DEVI void gload_lds16(const bf16_t* gsrc, bf16_t* ldst) {
  __builtin_amdgcn_global_load_lds(
      (const __attribute__((address_space(1))) uint32_t*)gsrc,
      (__attribute__((address_space(3))) uint32_t*)ldst,
      16, 0, 0);
}

// ---------------------------------------------------------------------------
// 256x256 tile, BK=64, 8 waves (2Mx4N), double-buffered LDS, 8-phase schedule.
// LDS swizzle: physical_col_byte = logical ^ 32*(row&4?1:0) ^ 64*(row&8?1:0),
// staged via linear global_load_lds dest + pre-swizzled global SOURCE col.
// vmcnt(4) once per K-tile (2 half-tiles in flight); drain only in tail.
// NO explicit lgkm waits: compiler inserts fine-grained per-MFMA waits.
// ---------------------------------------------------------------------------
template<int K>
__global__ __launch_bounds__(512, 2) void gemm256(
    const bf16_t* __restrict__ A,     // M x K row-major
    const bf16_t* __restrict__ BT,    // N x K row-major (pre-transposed W)
    const float* __restrict__ bias,
    const float* __restrict__ wtime,
    float t,
    bf16_t* __restrict__ C, int ldc,
    int M, int N)
{
  constexpr int NT = K / 64;          // K-tiles
  static_assert(NT >= 2, "need >=2 K-tiles");

  __shared__ __align__(16) bf16_t As[2][256][64];
  __shared__ __align__(16) bf16_t Bs[2][256][64];

  const int tid  = threadIdx.x;
  const int wave = tid >> 6;
  const int lane = tid & 63;
  const int wr = wave >> 2;           // 0..1 -> 128-row half
  const int wc = wave & 3;            // 0..3 -> 64-col strip

  // T1: XCD-aware bijective swizzle (gridDim.x % 8 == 0 by construction)
  int wg = blockIdx.x;
  {
    const int cpx = gridDim.x >> 3;
    wg = (wg & 7) * cpx + (wg >> 3);
  }
  const int nbn = N >> 8;
  const int bm = (wg / nbn) << 8;
  const int bn = (wg % nbn) << 8;

  // staging: dest row r = [buf*256 + h*128 +] wave*8 + (lane>>3)
  //   -> r&4 = lane&32-bit, r&8 = wave&1.  Pre-swizzle the SOURCE col:
  //   elem ^= ((lane&32)>>1)  (byte bit5)  ^ ((wave&1)<<5)  (byte bit6)
  const int srow = lane >> 3;
  const int scol = ((lane & 7) << 3) ^ ((lane & 32) >> 1) ^ ((wave & 1) << 5);
  const bf16_t* aS = A  + (size_t)(bm + wave * 8 + srow) * K + scol;
  const bf16_t* bS = BT + (size_t)(bn + wave * 8 + srow) * K + scol;
  bf16_t* aD = &As[0][0][0] + wave * 8 * 64;   // wave-uniform LDS base
  bf16_t* bD = &Bs[0][0][0] + wave * 8 * 64;

  // stage one half-tile (128 rows x 64 cols) = 2 load instrs
  auto stageHalf = [&](int kt, int isB, int h) {
    const int buf = kt & 1;
    const bf16_t* src = (isB ? bS : aS) + (size_t)(h * 128) * K + kt * 64;
    bf16_t*       dst = (isB ? bD : aD) + (buf * 256 + h * 128) * 64;
    gload_lds16(src,                 dst);
    gload_lds16(src + (size_t)64 * K, dst + 64 * 64);
  };

  const int fr = lane & 15;
  const int fq = lane >> 4;
  const int rsw = ((fr & 4) << 3) ^ ((fr & 8) << 3);   // byte-XOR from row bits

  bf16x8 af[8];        // A quadrant frags [m*2+kk]
  bf16x8 bfr[8];       // B frags [nh*4 + n*2 + kk]
  f32x4  acc[8][4] = {};

  auto lda_frag = [&](int buf, int mh) {
    const char* base = (const char*)&As[buf][0][0];
#pragma unroll
    for (int m = 0; m < 4; ++m)
#pragma unroll
      for (int kk = 0; kk < 2; ++kk) {
        int r  = wr * 128 + (mh * 4 + m) * 16 + fr;
        int cb = (kk * 64 + fq * 16) ^ rsw;
        af[m * 2 + kk] = *(const bf16x8*)(base + r * 128 + cb);
      }
  };
  auto ldb_frag = [&](int buf, int nh) {
    const char* base = (const char*)&Bs[buf][0][0];
#pragma unroll
    for (int n = 0; n < 2; ++n)
#pragma unroll
      for (int kk = 0; kk < 2; ++kk) {
        int r  = wc * 64 + (nh * 2 + n) * 16 + fr;
        int cb = (kk * 64 + fq * 16) ^ rsw;
        bfr[nh * 4 + n * 2 + kk] = *(const bf16x8*)(base + r * 128 + cb);
      }
  };
  auto mma_quad = [&](int mh, int nh) {
    __builtin_amdgcn_s_setprio(1);
#pragma unroll
    for (int m = 0; m < 4; ++m)
#pragma unroll
      for (int n = 0; n < 2; ++n)
#pragma unroll
        for (int kk = 0; kk < 2; ++kk)
          acc[mh * 4 + m][nh * 2 + n] = __builtin_amdgcn_mfma_f32_16x16x32_bf16(
              af[m * 2 + kk], bfr[nh * 4 + n * 2 + kk],
              acc[mh * 4 + m][nh * 2 + n], 0, 0, 0);
    __builtin_amdgcn_s_setprio(0);
  };

  // prologue: tile0 full + tile1 {Bh0, Ah0}  (matches steady-state p2/p3 order)
  stageHalf(0, 0, 0); stageHalf(0, 1, 0);
  stageHalf(0, 0, 1); stageHalf(0, 1, 1);
  stageHalf(1, 1, 0); stageHalf(1, 0, 0);
  asm volatile("s_waitcnt vmcnt(4)" ::: "memory");   // tile0 resident
  __builtin_amdgcn_s_barrier();

  for (int t2 = 0; t2 < NT; ++t2) {
    const int buf = t2 & 1;
    // phase 0: quadrant (0,0); stage Ah1(t2+1) -> other buf
    lda_frag(buf, 0);
    ldb_frag(buf, 0);
    if (t2 + 1 < NT) stageHalf(t2 + 1, 0, 1);
    __builtin_amdgcn_s_barrier();
    mma_quad(0, 0);
    __builtin_amdgcn_s_barrier();
    // phase 1: quadrant (0,1); stage Bh1(t2+1) -> other buf
    ldb_frag(buf, 1);
    if (t2 + 1 < NT) stageHalf(t2 + 1, 1, 1);
    __builtin_amdgcn_s_barrier();
    mma_quad(0, 1);
    __builtin_amdgcn_s_barrier();
    // phase 2: quadrant (1,0); stage Bh0(t2+2) -> current buf (B last read p1)
    lda_frag(buf, 1);
    if (t2 + 2 < NT) stageHalf(t2 + 2, 1, 0);
    __builtin_amdgcn_s_barrier();
    mma_quad(1, 0);
    __builtin_amdgcn_s_barrier();
    // phase 3: quadrant (1,1); stage Ah0(t2+2) -> current buf (A last read p2)
    if (t2 + 2 < NT) {
      stageHalf(t2 + 2, 0, 0);
      asm volatile("s_waitcnt vmcnt(4)" ::: "memory");  // tile t2+1 resident
    } else {
      asm volatile("s_waitcnt vmcnt(0)" ::: "memory");
    }
    __builtin_amdgcn_s_barrier();
    mma_quad(1, 1);
    __builtin_amdgcn_s_barrier();
  }

  // epilogue: bias(t) + ReLU, bf16 out
#pragma unroll
  for (int n = 0; n < 4; ++n) {
    const int gcol = bn + wc * 64 + n * 16 + fr;
    const float bv = bias[gcol] + t * wtime[gcol];
#pragma unroll
    for (int m = 0; m < 8; ++m) {
      const int grow0 = bm + wr * 128 + m * 16 + (fq << 2);
#pragma unroll
      for (int r = 0; r < 4; ++r) {
        float v = acc[m][n][r] + bv;
        v = v > 0.0f ? v : 0.0f;
        C[(size_t)(grow0 + r) * ldc + gcol] = (bf16_t)v;
      }
    }
  }
}

// ---------------------------------------------------------------------------
// 128^2 kernel for layer 0 (K=64), full bank-spread swizzle.
// ---------------------------------------------------------------------------
template<int BM, int BN, int BK, int WROWS, int WCOLS, bool RELU, bool OUT_BF16>
__global__ __launch_bounds__(256) void gemm_bt(
    const bf16_t* __restrict__ A, int lda,
    const bf16_t* __restrict__ BT,
    const float* __restrict__ bias,
    const float* __restrict__ wtime,
    float t,
    void* __restrict__ Cv, int ldc,
    int M, int K)
{
  static_assert(BK == 64, "swizzle assumes BK=64");
  constexpr int MR  = BM / WROWS / 16;
  constexpr int NR  = BN / WCOLS / 16;
  constexpr int TPR = BK / 8;        // 8
  constexpr int RPW = 64 / TPR;      // 8
  constexpr int RPL = 4 * RPW;       // 32
  static_assert(BM % RPL == 0 && BN % RPL == 0, "tile staging mismatch");

  __shared__ bf16_t As[BM][BK];
  __shared__ bf16_t Bs[BN][BK];

  const int tid  = threadIdx.x;
  const int wave = tid >> 6;
  const int lane = tid & 63;
  const int wr = wave / WCOLS;
  const int wc = wave % WCOLS;
  const int bm = blockIdx.x * BM;
  const int bn = blockIdx.y * BN;
  const int lrow = lane >> 3;
  const int lcol = (((lane & 7) << 3) ^ ((lane & 32) >> 1) ^ ((wave & 1) << 5));

  const int fr = lane & 15;
  const int fq = lane >> 4;
  const int esw = ((fr & 4) << 2) ^ ((fr & 8) << 2);  // element-XOR from row bits

  f32x4 acc[MR][NR] = {};

  for (int k0 = 0; k0 < K; k0 += BK) {
#pragma unroll
    for (int i = 0; i < BM / RPL; ++i) {
      const int rb = i * RPL + wave * RPW;
      gload_lds16(&A[(size_t)(bm + rb + lrow) * lda + k0 + lcol], &As[rb][0]);
    }
#pragma unroll
    for (int i = 0; i < BN / RPL; ++i) {
      const int rb = i * RPL + wave * RPW;
      gload_lds16(&BT[(size_t)(bn + rb + lrow) * K + k0 + lcol], &Bs[rb][0]);
    }
    __syncthreads();
#pragma unroll
    for (int kk = 0; kk < BK / 32; ++kk) {
      bf16x8 af[MR], bfr[NR];
      const int ecol = (kk * 32 + fq * 8) ^ esw;
#pragma unroll
      for (int m = 0; m < MR; ++m)
        af[m] = *(const bf16x8*)&As[wr * (BM / WROWS) + m * 16 + fr][ecol];
#pragma unroll
      for (int n = 0; n < NR; ++n)
        bfr[n] = *(const bf16x8*)&Bs[wc * (BN / WCOLS) + n * 16 + fr][ecol];
#pragma unroll
      for (int m = 0; m < MR; ++m)
#pragma unroll
        for (int n = 0; n < NR; ++n)
          acc[m][n] = __builtin_amdgcn_mfma_f32_16x16x32_bf16(
              af[m], bfr[n], acc[m][n], 0, 0, 0);
    }
    __syncthreads();
  }

#pragma unroll
  for (int n = 0; n < NR; ++n) {
    const int gcol = bn + wc * (BN / WCOLS) + n * 16 + fr;
    const float bv = bias[gcol] + t * wtime[gcol];
#pragma unroll
    for (int m = 0; m < MR; ++m) {
      const int grow0 = bm + wr * (BM / WROWS) + m * 16 + (fq << 2);
#pragma unroll
      for (int r = 0; r < 4; ++r) {
        float v = acc[m][n][r] + bv;
        if (RELU) v = v > 0.0f ? v : 0.0f;
        if constexpr (OUT_BF16)
          ((bf16_t*)Cv)[(size_t)(grow0 + r) * ldc + gcol] = (bf16_t)v;
        else
          ((float*)Cv)[(size_t)(grow0 + r) * ldc + gcol] = v;
      }
    }
  }
}

// ---------------------------------------------------------------------------
// Layer 4 (N=64, K=1024) with RK4 combine fused into the epilogue.
// BM=64, BN=64, 4 waves (2x2) -> 512 blocks = 2 blocks/CU.  Swizzled LDS.
// ---------------------------------------------------------------------------
__global__ __launch_bounds__(256) void gemm_l4_rk4(
    const bf16_t* __restrict__ A, int lda,
    const bf16_t* __restrict__ BT,
    const float* __restrict__ bias,
    const float* __restrict__ wtime,
    float t,
    float* __restrict__ y, float* __restrict__ accb,
    bf16_t* __restrict__ ybf,
    float ca, float cs, int mode,
    int M, int K)
{
  constexpr int BM = 64, BN = 64, BK = 64;
  constexpr int MR = 2, NR = 2;

  __shared__ bf16_t As[BM][BK];
  __shared__ bf16_t Bs[BN][BK];

  const int tid  = threadIdx.x;
  const int wave = tid >> 6;
  const int lane = tid & 63;
  const int wr = wave >> 1;
  const int wc = wave & 1;
  const int bm = blockIdx.x * BM;
  const int lrow = lane >> 3;
  const int lcol = (((lane & 7) << 3) ^ ((lane & 32) >> 1) ^ ((wave & 1) << 5));

  const int fr = lane & 15;
  const int fq = lane >> 4;
  const int esw = ((fr & 4) << 2) ^ ((fr & 8) << 2);

  f32x4 acc[MR][NR] = {};

  for (int k0 = 0; k0 < K; k0 += BK) {
#pragma unroll
    for (int i = 0; i < 2; ++i) {
      const int rb = i * 32 + wave * 8;
      gload_lds16(&A[(size_t)(bm + rb + lrow) * lda + k0 + lcol], &As[rb][0]);
    }
#pragma unroll
    for (int i = 0; i < 2; ++i) {
      const int rb = i * 32 + wave * 8;
      gload_lds16(&BT[(size_t)(rb + lrow) * K + k0 + lcol], &Bs[rb][0]);
    }
    __syncthreads();
#pragma unroll
    for (int kk = 0; kk < 2; ++kk) {
      bf16x8 af[MR], bfr[NR];
      const int ecol = (kk * 32 + fq * 8) ^ esw;
#pragma unroll
      for (int m = 0; m < MR; ++m)
        af[m] = *(const bf16x8*)&As[wr * 32 + m * 16 + fr][ecol];
#pragma unroll
      for (int n = 0; n < NR; ++n)
        bfr[n] = *(const bf16x8*)&Bs[wc * 32 + n * 16 + fr][ecol];
#pragma unroll
      for (int m = 0; m < MR; ++m)
#pragma unroll
        for (int n = 0; n < NR; ++n)
          acc[m][n] = __builtin_amdgcn_mfma_f32_16x16x32_bf16(
              af[m], bfr[n], acc[m][n], 0, 0, 0);
    }
    __syncthreads();
  }

#pragma unroll
  for (int n = 0; n < NR; ++n) {
    const int gcol = wc * 32 + n * 16 + fr;
    const float bv = bias[gcol] + t * wtime[gcol];
#pragma unroll
    for (int m = 0; m < MR; ++m) {
      const int grow0 = bm + wr * 32 + m * 16 + (fq << 2);
#pragma unroll
      for (int r = 0; r < 4; ++r) {
        const float kv = acc[m][n][r] + bv;
        const size_t o = (size_t)(grow0 + r) * 64 + gcol;
        if (mode == 0) {
          accb[o] = kv;
          ybf[o] = (bf16_t)(y[o] + cs * kv);
        } else if (mode == 1) {
          accb[o] += ca * kv;
          ybf[o] = (bf16_t)(y[o] + cs * kv);
        } else {
          const float ny = y[o] + cs * (accb[o] + kv);
          y[o] = ny;
          ybf[o] = (bf16_t)ny;
        }
      }
    }
  }
}

// ---------------------------------------------------------------------------
__global__ void prep_weight(const float* __restrict__ W, const float* __restrict__ b,
                            bf16_t* __restrict__ WT, float* __restrict__ bias,
                            float* __restrict__ wtime,
                            int K, int N, int Kpad, int Npad)
{
  int idx = blockIdx.x * 256 + threadIdx.x;
  int total = Npad * Kpad;
  if (idx < total) {
    int n = idx / Kpad, k = idx % Kpad;
    float v = (n < N && k < K) ? W[(size_t)k * N + n] : 0.0f;
    WT[idx] = (bf16_t)v;
  }
  if (idx < Npad) {
    bias[idx]  = (idx < N) ? b[idx] : 0.0f;
    wtime[idx] = (idx < N) ? W[(size_t)K * N + idx] : 0.0f;
  }
}

__global__ void init_y(const float* __restrict__ x, float* __restrict__ y,
                       bf16_t* __restrict__ ybf, int M)
{
  int i = blockIdx.x * 256 + threadIdx.x;
  if (i < M * 64) {
    int m = i >> 6, c = i & 63;
    float v = (c < 2) ? x[m * 2 + c] : 0.0f;
    y[i] = v;
    ybf[i] = (bf16_t)v;
  }
}

__global__ void extract_out(const float* __restrict__ y, float* __restrict__ out, int M)
{
  int i = blockIdx.x * 256 + threadIdx.x;
  if (i < M * 3) {
    int m = i / 3, c = i % 3;
    out[i] = y[(size_t)m * 64 + c];
  }
}

extern "C" void kernel_launch(void* const* d_in, const int* in_sizes, int n_in,
                              void* d_out, int out_size, void* d_ws, size_t ws_size,
                              hipStream_t stream)
{
  (void)in_sizes; (void)n_in; (void)out_size; (void)ws_size;
  const int M = 32768;

  const float* x = (const float*)d_in[0];
  const float* Wp[5]; const float* bp[5];
  for (int i = 0; i < 5; ++i) {
    Wp[i] = (const float*)d_in[1 + 2 * i];
    bp[i] = (const float*)d_in[2 + 2 * i];
  }

  char* ws = (char*)d_ws; size_t off = 0;
  auto alloc = [&](size_t bytes) -> char* {
    char* p = ws + off; off += (bytes + 255) & ~(size_t)255; return p;
  };

  bf16_t* WT[5];
  WT[0] = (bf16_t*)alloc((size_t)1024 * 64 * 2);
  WT[1] = (bf16_t*)alloc((size_t)1024 * 1024 * 2);
  WT[2] = (bf16_t*)alloc((size_t)1024 * 1024 * 2);
  WT[3] = (bf16_t*)alloc((size_t)1024 * 1024 * 2);
  WT[4] = (bf16_t*)alloc((size_t)64 * 1024 * 2);
  float* bias[5]; float* wtm[5];
  for (int i = 0; i < 5; ++i) {
    int Np = (i == 4) ? 64 : 1024;
    bias[i] = (float*)alloc((size_t)Np * 4);
    wtm[i]  = (float*)alloc((size_t)Np * 4);
  }
  float*  y    = (float*)alloc((size_t)M * 64 * 4);
  float*  accb = (float*)alloc((size_t)M * 64 * 4);
  bf16_t* ybf  = (bf16_t*)alloc((size_t)M * 64 * 2);
  bf16_t* act0 = (bf16_t*)alloc((size_t)M * 1024 * 2);
  bf16_t* act1 = (bf16_t*)alloc((size_t)M * 1024 * 2);

  const int Kd[5]  = {50, 1024, 1024, 1024, 1024};
  const int Nd[5]  = {1024, 1024, 1024, 1024, 50};
  const int Kpd[5] = {64, 1024, 1024, 1024, 1024};
  const int Npd[5] = {1024, 1024, 1024, 1024, 64};
  for (int i = 0; i < 5; ++i) {
    int tot = Npd[i] * Kpd[i];
    prep_weight<<<dim3((tot + 255) / 256), 256, 0, stream>>>(
        Wp[i], bp[i], WT[i], bias[i], wtm[i], Kd[i], Nd[i], Kpd[i], Npd[i]);
  }

  init_y<<<dim3((M * 64 + 255) / 256), 256, 0, stream>>>(x, y, ybf, M);

  const float dtv = 1.0f / 32.0f;
  dim3 gL0(M / 128, 1024 / 128);        // 2048 blocks
  dim3 g256(M / 256 * (1024 / 256));    // 512 blocks, %8 == 0
  dim3 gL4(M / 64);                     // 512 blocks = 2/CU

  auto run_net = [&](float t, float ca, float cs, int mode) {
    gemm_bt<128,128,64,2,2,true,true><<<gL0, 256, 0, stream>>>(
        ybf, 64, WT[0], bias[0], wtm[0], t, act0, 1024, M, 64);
    gemm256<1024><<<g256, 512, 0, stream>>>(
        act0, WT[1], bias[1], wtm[1], t, act1, 1024, M, 1024);
    gemm256<1024><<<g256, 512, 0, stream>>>(
        act1, WT[2], bias[2], wtm[2], t, act0, 1024, M, 1024);
    gemm256<1024><<<g256, 512, 0, stream>>>(
        act0, WT[3], bias[3], wtm[3], t, act1, 1024, M, 1024);
    gemm_l4_rk4<<<gL4, 256, 0, stream>>>(
        act1, 1024, WT[4], bias[4], wtm[4], t,
        y, accb, ybf, ca, cs, mode, M, 1024);
  };

  for (int i = 0; i < 32; ++i) {
    const float t0 = i * dtv;
    const float tm = t0 + 0.5f * dtv;
    const float t1 = t0 + dtv;
    run_net(t0, 0.0f, 0.5f * dtv, 0);   // k1
    run_net(tm, 2.0f, 0.5f * dtv, 1);   // k2
    run_net(tm, 2.0f, dtv,        1);   // k3
    run_net(t1, 0.0f, dtv / 6.0f, 2);   // k4
  }

  extract_out<<<dim3((M * 3 + 255) / 256), 256, 0, stream>>>(y, (float*)d_out, M);
}

// Round 8
// 35167.566 us; speedup vs baseline: 1.2158x; 1.1185x over previous
//
#include <hip/hip_runtime.h>
#include <hip/hip_bf16.h>
#include <stdint.h>

// Neural ODE (RK4, 32 steps) over a 5-layer MLP, B=32768, VAR_DIM=50 (pad 64).
// bf16 MFMA GEMMs (16x16x32), fp32 accum, fp32 state y.
// concat(h,t) @ W == h @ W[:K] + (b + t*W[K]) -> time column folded into bias.
// r7: gemm256 restructured to ONE barrier per K-tile with software-pipelined
//     fragment reads. The old 8-barrier/tile phase structure forced DS-pipe
//     (2300 cyc/tile) and MFMA-pipe (2480 cyc/tile) to alternate (sum ~6300);
//     now they overlap (max ~3300). Hazard ledger: reads of tile T drain via
//     compiler lgkm waits before the mid-tile barrier; staging of T+1 writes
//     the other buffer after it; cross-tile reads follow vmcnt(0)+barrier.

typedef __bf16 bf16_t;
typedef bf16_t bf16x8 __attribute__((ext_vector_type(8)));
typedef float  f32x4  __attribute__((ext_vector_type(4)));

#define DEVI static __device__ __forceinline__

DEVI void gload_lds16(const bf16_t* gsrc, bf16_t* ldst) {
  __builtin_amdgcn_global_load_lds(
      (const __attribute__((address_space(1))) uint32_t*)gsrc,
      (__attribute__((address_space(3))) uint32_t*)ldst,
      16, 0, 0);
}

// ---------------------------------------------------------------------------
// 256x256 tile, BK=64, 8 waves (2Mx4N), double-buffered LDS.
// LDS swizzle: physical_col_byte = logical ^ 32*(row&4) ^ 64*(row&8) bits,
// staged via linear global_load_lds dest + pre-swizzled global SOURCE col.
// Per K-tile: stage T+1 (8 gloads) at top; quadrant MFMAs consume fragments
// issued one quadrant earlier; vmcnt(0)+barrier mid-tile; cross-tile reads
// for T+1 overlap quadrant-3 MFMAs. No explicit lgkm waits (compiler).
// ---------------------------------------------------------------------------
template<int K>
__global__ __launch_bounds__(512, 2) void gemm256(
    const bf16_t* __restrict__ A,     // M x K row-major
    const bf16_t* __restrict__ BT,    // N x K row-major (pre-transposed W)
    const float* __restrict__ bias,
    const float* __restrict__ wtime,
    float t,
    bf16_t* __restrict__ C, int ldc,
    int M, int N)
{
  constexpr int NT = K / 64;          // K-tiles
  static_assert(NT >= 2, "need >=2 K-tiles");

  __shared__ __align__(16) bf16_t As[2][256][64];
  __shared__ __align__(16) bf16_t Bs[2][256][64];

  const int tid  = threadIdx.x;
  const int wave = tid >> 6;
  const int lane = tid & 63;
  const int wr = wave >> 2;           // 0..1 -> 128-row half
  const int wc = wave & 3;            // 0..3 -> 64-col strip

  // T1: XCD-aware bijective swizzle (gridDim.x % 8 == 0 by construction)
  int wg = blockIdx.x;
  {
    const int cpx = gridDim.x >> 3;
    wg = (wg & 7) * cpx + (wg >> 3);
  }
  const int nbn = N >> 8;
  const int bm = (wg / nbn) << 8;
  const int bn = (wg % nbn) << 8;

  // staging: dest row r = [buf*256 + h*128 +] wave*8 + (lane>>3)
  //   -> r&4 = lane&32-bit, r&8 = wave&1.  Pre-swizzled SOURCE col.
  const int srow = lane >> 3;
  const int scol = ((lane & 7) << 3) ^ ((lane & 32) >> 1) ^ ((wave & 1) << 5);
  const bf16_t* aS = A  + (size_t)(bm + wave * 8 + srow) * K + scol;
  const bf16_t* bS = BT + (size_t)(bn + wave * 8 + srow) * K + scol;
  bf16_t* aD = &As[0][0][0] + wave * 8 * 64;   // wave-uniform LDS base
  bf16_t* bD = &Bs[0][0][0] + wave * 8 * 64;

  auto stageHalf = [&](int kt, int isB, int h) {
    const int buf = kt & 1;
    const bf16_t* src = (isB ? bS : aS) + (size_t)(h * 128) * K + kt * 64;
    bf16_t*       dst = (isB ? bD : aD) + (buf * 256 + h * 128) * 64;
    gload_lds16(src,                  dst);
    gload_lds16(src + (size_t)64 * K, dst + 64 * 64);
  };
  auto stageTile = [&](int kt) {
    stageHalf(kt, 0, 0); stageHalf(kt, 0, 1);
    stageHalf(kt, 1, 0); stageHalf(kt, 1, 1);
  };

  const int fr = lane & 15;
  const int fq = lane >> 4;
  const int rsw = ((fr & 4) << 3) ^ ((fr & 8) << 3);   // byte-XOR from row bits

  bf16x8 ah0[8], ah1[8];   // A frags for mh=0 / mh=1  [m*2+kk]
  bf16x8 bh0[4], bh1[4];   // B frags for nh=0 / nh=1  [n*2+kk]
  f32x4  acc[8][4] = {};

  auto lda_into = [&](bf16x8 (&dst)[8], int buf, int mh) {
    const char* base = (const char*)&As[buf][0][0];
#pragma unroll
    for (int m = 0; m < 4; ++m)
#pragma unroll
      for (int kk = 0; kk < 2; ++kk) {
        int r  = wr * 128 + (mh * 4 + m) * 16 + fr;
        int cb = (kk * 64 + fq * 16) ^ rsw;
        dst[m * 2 + kk] = *(const bf16x8*)(base + r * 128 + cb);
      }
  };
  auto ldb_into = [&](bf16x8 (&dst)[4], int buf, int nh) {
    const char* base = (const char*)&Bs[buf][0][0];
#pragma unroll
    for (int n = 0; n < 2; ++n)
#pragma unroll
      for (int kk = 0; kk < 2; ++kk) {
        int r  = wc * 64 + (nh * 2 + n) * 16 + fr;
        int cb = (kk * 64 + fq * 16) ^ rsw;
        dst[n * 2 + kk] = *(const bf16x8*)(base + r * 128 + cb);
      }
  };
  auto mma_quad = [&](bf16x8 (&a)[8], bf16x8 (&b)[4], int mh, int nh) {
    __builtin_amdgcn_s_setprio(1);
#pragma unroll
    for (int m = 0; m < 4; ++m)
#pragma unroll
      for (int n = 0; n < 2; ++n)
#pragma unroll
        for (int kk = 0; kk < 2; ++kk)
          acc[mh * 4 + m][nh * 2 + n] = __builtin_amdgcn_mfma_f32_16x16x32_bf16(
              a[m * 2 + kk], b[n * 2 + kk],
              acc[mh * 4 + m][nh * 2 + n], 0, 0, 0);
    __builtin_amdgcn_s_setprio(0);
  };

  // prologue: stage tile0, drain, read tile0 mh0/nh0 fragments
  stageTile(0);
  asm volatile("s_waitcnt vmcnt(0)" ::: "memory");
  __builtin_amdgcn_s_barrier();
  lda_into(ah0, 0, 0);
  ldb_into(bh0, 0, 0);

  for (int t2 = 0; t2 < NT; ++t2) {
    const int buf = t2 & 1;
    if (t2 + 1 < NT) stageTile(t2 + 1);   // 8 gloads -> other buffer
    ldb_into(bh1, buf, 1);                // 4 reads (this tile)
    mma_quad(ah0, bh0, 0, 0);             // q0 (ah0/bh0 issued last tile q3)
    lda_into(ah1, buf, 1);                // 8 reads (this tile)
    mma_quad(ah0, bh1, 0, 1);             // q1 (bh1 issued above, 1 quad ago)
    mma_quad(ah1, bh0, 1, 0);             // q2 (ah1 issued 1 quad ago)
    if (t2 + 1 < NT) {
      asm volatile("s_waitcnt vmcnt(0)" ::: "memory");  // T+1 staged (ours)
      __builtin_amdgcn_s_barrier();                     // all waves' stages + reads done
      lda_into(ah0, buf ^ 1, 0);          // cross-tile reads overlap q3 MFMAs
      ldb_into(bh0, buf ^ 1, 0);
    }
    mma_quad(ah1, bh1, 1, 1);             // q3 (operands already in regs)
  }

  // epilogue: bias(t) + ReLU, bf16 out
#pragma unroll
  for (int n = 0; n < 4; ++n) {
    const int gcol = bn + wc * 64 + n * 16 + fr;
    const float bv = bias[gcol] + t * wtime[gcol];
#pragma unroll
    for (int m = 0; m < 8; ++m) {
      const int grow0 = bm + wr * 128 + m * 16 + (fq << 2);
#pragma unroll
      for (int r = 0; r < 4; ++r) {
        float v = acc[m][n][r] + bv;
        v = v > 0.0f ? v : 0.0f;
        C[(size_t)(grow0 + r) * ldc + gcol] = (bf16_t)v;
      }
    }
  }
}

// ---------------------------------------------------------------------------
// 128^2 kernel for layer 0 (K=64), full bank-spread swizzle.
// ---------------------------------------------------------------------------
template<int BM, int BN, int BK, int WROWS, int WCOLS, bool RELU, bool OUT_BF16>
__global__ __launch_bounds__(256) void gemm_bt(
    const bf16_t* __restrict__ A, int lda,
    const bf16_t* __restrict__ BT,
    const float* __restrict__ bias,
    const float* __restrict__ wtime,
    float t,
    void* __restrict__ Cv, int ldc,
    int M, int K)
{
  static_assert(BK == 64, "swizzle assumes BK=64");
  constexpr int MR  = BM / WROWS / 16;
  constexpr int NR  = BN / WCOLS / 16;
  constexpr int TPR = BK / 8;        // 8
  constexpr int RPW = 64 / TPR;      // 8
  constexpr int RPL = 4 * RPW;       // 32
  static_assert(BM % RPL == 0 && BN % RPL == 0, "tile staging mismatch");

  __shared__ bf16_t As[BM][BK];
  __shared__ bf16_t Bs[BN][BK];

  const int tid  = threadIdx.x;
  const int wave = tid >> 6;
  const int lane = tid & 63;
  const int wr = wave / WCOLS;
  const int wc = wave % WCOLS;
  const int bm = blockIdx.x * BM;
  const int bn = blockIdx.y * BN;
  const int lrow = lane >> 3;
  const int lcol = (((lane & 7) << 3) ^ ((lane & 32) >> 1) ^ ((wave & 1) << 5));

  const int fr = lane & 15;
  const int fq = lane >> 4;
  const int esw = ((fr & 4) << 2) ^ ((fr & 8) << 2);  // element-XOR from row bits

  f32x4 acc[MR][NR] = {};

  for (int k0 = 0; k0 < K; k0 += BK) {
#pragma unroll
    for (int i = 0; i < BM / RPL; ++i) {
      const int rb = i * RPL + wave * RPW;
      gload_lds16(&A[(size_t)(bm + rb + lrow) * lda + k0 + lcol], &As[rb][0]);
    }
#pragma unroll
    for (int i = 0; i < BN / RPL; ++i) {
      const int rb = i * RPL + wave * RPW;
      gload_lds16(&BT[(size_t)(bn + rb + lrow) * K + k0 + lcol], &Bs[rb][0]);
    }
    __syncthreads();
#pragma unroll
    for (int kk = 0; kk < BK / 32; ++kk) {
      bf16x8 af[MR], bfr[NR];
      const int ecol = (kk * 32 + fq * 8) ^ esw;
#pragma unroll
      for (int m = 0; m < MR; ++m)
        af[m] = *(const bf16x8*)&As[wr * (BM / WROWS) + m * 16 + fr][ecol];
#pragma unroll
      for (int n = 0; n < NR; ++n)
        bfr[n] = *(const bf16x8*)&Bs[wc * (BN / WCOLS) + n * 16 + fr][ecol];
#pragma unroll
      for (int m = 0; m < MR; ++m)
#pragma unroll
        for (int n = 0; n < NR; ++n)
          acc[m][n] = __builtin_amdgcn_mfma_f32_16x16x32_bf16(
              af[m], bfr[n], acc[m][n], 0, 0, 0);
    }
    __syncthreads();
  }

#pragma unroll
  for (int n = 0; n < NR; ++n) {
    const int gcol = bn + wc * (BN / WCOLS) + n * 16 + fr;
    const float bv = bias[gcol] + t * wtime[gcol];
#pragma unroll
    for (int m = 0; m < MR; ++m) {
      const int grow0 = bm + wr * (BM / WROWS) + m * 16 + (fq << 2);
#pragma unroll
      for (int r = 0; r < 4; ++r) {
        float v = acc[m][n][r] + bv;
        if (RELU) v = v > 0.0f ? v : 0.0f;
        if constexpr (OUT_BF16)
          ((bf16_t*)Cv)[(size_t)(grow0 + r) * ldc + gcol] = (bf16_t)v;
        else
          ((float*)Cv)[(size_t)(grow0 + r) * ldc + gcol] = v;
      }
    }
  }
}

// ---------------------------------------------------------------------------
// Layer 4 (N=64, K=1024) with RK4 combine fused into the epilogue.
// BM=64, BN=64, 4 waves (2x2) -> 512 blocks = 2 blocks/CU.  Swizzled LDS.
// ---------------------------------------------------------------------------
__global__ __launch_bounds__(256) void gemm_l4_rk4(
    const bf16_t* __restrict__ A, int lda,
    const bf16_t* __restrict__ BT,
    const float* __restrict__ bias,
    const float* __restrict__ wtime,
    float t,
    float* __restrict__ y, float* __restrict__ accb,
    bf16_t* __restrict__ ybf,
    float ca, float cs, int mode,
    int M, int K)
{
  constexpr int BM = 64, BN = 64, BK = 64;
  constexpr int MR = 2, NR = 2;

  __shared__ bf16_t As[BM][BK];
  __shared__ bf16_t Bs[BN][BK];

  const int tid  = threadIdx.x;
  const int wave = tid >> 6;
  const int lane = tid & 63;
  const int wr = wave >> 1;
  const int wc = wave & 1;
  const int bm = blockIdx.x * BM;
  const int lrow = lane >> 3;
  const int lcol = (((lane & 7) << 3) ^ ((lane & 32) >> 1) ^ ((wave & 1) << 5));

  const int fr = lane & 15;
  const int fq = lane >> 4;
  const int esw = ((fr & 4) << 2) ^ ((fr & 8) << 2);

  f32x4 acc[MR][NR] = {};

  for (int k0 = 0; k0 < K; k0 += BK) {
#pragma unroll
    for (int i = 0; i < 2; ++i) {
      const int rb = i * 32 + wave * 8;
      gload_lds16(&A[(size_t)(bm + rb + lrow) * lda + k0 + lcol], &As[rb][0]);
    }
#pragma unroll
    for (int i = 0; i < 2; ++i) {
      const int rb = i * 32 + wave * 8;
      gload_lds16(&BT[(size_t)(rb + lrow) * K + k0 + lcol], &Bs[rb][0]);
    }
    __syncthreads();
#pragma unroll
    for (int kk = 0; kk < 2; ++kk) {
      bf16x8 af[MR], bfr[NR];
      const int ecol = (kk * 32 + fq * 8) ^ esw;
#pragma unroll
      for (int m = 0; m < MR; ++m)
        af[m] = *(const bf16x8*)&As[wr * 32 + m * 16 + fr][ecol];
#pragma unroll
      for (int n = 0; n < NR; ++n)
        bfr[n] = *(const bf16x8*)&Bs[wc * 32 + n * 16 + fr][ecol];
#pragma unroll
      for (int m = 0; m < MR; ++m)
#pragma unroll
        for (int n = 0; n < NR; ++n)
          acc[m][n] = __builtin_amdgcn_mfma_f32_16x16x32_bf16(
              af[m], bfr[n], acc[m][n], 0, 0, 0);
    }
    __syncthreads();
  }

#pragma unroll
  for (int n = 0; n < NR; ++n) {
    const int gcol = wc * 32 + n * 16 + fr;
    const float bv = bias[gcol] + t * wtime[gcol];
#pragma unroll
    for (int m = 0; m < MR; ++m) {
      const int grow0 = bm + wr * 32 + m * 16 + (fq << 2);
#pragma unroll
      for (int r = 0; r < 4; ++r) {
        const float kv = acc[m][n][r] + bv;
        const size_t o = (size_t)(grow0 + r) * 64 + gcol;
        if (mode == 0) {
          accb[o] = kv;
          ybf[o] = (bf16_t)(y[o] + cs * kv);
        } else if (mode == 1) {
          accb[o] += ca * kv;
          ybf[o] = (bf16_t)(y[o] + cs * kv);
        } else {
          const float ny = y[o] + cs * (accb[o] + kv);
          y[o] = ny;
          ybf[o] = (bf16_t)ny;
        }
      }
    }
  }
}

// ---------------------------------------------------------------------------
__global__ void prep_weight(const float* __restrict__ W, const float* __restrict__ b,
                            bf16_t* __restrict__ WT, float* __restrict__ bias,
                            float* __restrict__ wtime,
                            int K, int N, int Kpad, int Npad)
{
  int idx = blockIdx.x * 256 + threadIdx.x;
  int total = Npad * Kpad;
  if (idx < total) {
    int n = idx / Kpad, k = idx % Kpad;
    float v = (n < N && k < K) ? W[(size_t)k * N + n] : 0.0f;
    WT[idx] = (bf16_t)v;
  }
  if (idx < Npad) {
    bias[idx]  = (idx < N) ? b[idx] : 0.0f;
    wtime[idx] = (idx < N) ? W[(size_t)K * N + idx] : 0.0f;
  }
}

__global__ void init_y(const float* __restrict__ x, float* __restrict__ y,
                       bf16_t* __restrict__ ybf, int M)
{
  int i = blockIdx.x * 256 + threadIdx.x;
  if (i < M * 64) {
    int m = i >> 6, c = i & 63;
    float v = (c < 2) ? x[m * 2 + c] : 0.0f;
    y[i] = v;
    ybf[i] = (bf16_t)v;
  }
}

__global__ void extract_out(const float* __restrict__ y, float* __restrict__ out, int M)
{
  int i = blockIdx.x * 256 + threadIdx.x;
  if (i < M * 3) {
    int m = i / 3, c = i % 3;
    out[i] = y[(size_t)m * 64 + c];
  }
}

extern "C" void kernel_launch(void* const* d_in, const int* in_sizes, int n_in,
                              void* d_out, int out_size, void* d_ws, size_t ws_size,
                              hipStream_t stream)
{
  (void)in_sizes; (void)n_in; (void)out_size; (void)ws_size;
  const int M = 32768;

  const float* x = (const float*)d_in[0];
  const float* Wp[5]; const float* bp[5];
  for (int i = 0; i < 5; ++i) {
    Wp[i] = (const float*)d_in[1 + 2 * i];
    bp[i] = (const float*)d_in[2 + 2 * i];
  }

  char* ws = (char*)d_ws; size_t off = 0;
  auto alloc = [&](size_t bytes) -> char* {
    char* p = ws + off; off += (bytes + 255) & ~(size_t)255; return p;
  };

  bf16_t* WT[5];
  WT[0] = (bf16_t*)alloc((size_t)1024 * 64 * 2);
  WT[1] = (bf16_t*)alloc((size_t)1024 * 1024 * 2);
  WT[2] = (bf16_t*)alloc((size_t)1024 * 1024 * 2);
  WT[3] = (bf16_t*)alloc((size_t)1024 * 1024 * 2);
  WT[4] = (bf16_t*)alloc((size_t)64 * 1024 * 2);
  float* bias[5]; float* wtm[5];
  for (int i = 0; i < 5; ++i) {
    int Np = (i == 4) ? 64 : 1024;
    bias[i] = (float*)alloc((size_t)Np * 4);
    wtm[i]  = (float*)alloc((size_t)Np * 4);
  }
  float*  y    = (float*)alloc((size_t)M * 64 * 4);
  float*  accb = (float*)alloc((size_t)M * 64 * 4);
  bf16_t* ybf  = (bf16_t*)alloc((size_t)M * 64 * 2);
  bf16_t* act0 = (bf16_t*)alloc((size_t)M * 1024 * 2);
  bf16_t* act1 = (bf16_t*)alloc((size_t)M * 1024 * 2);

  const int Kd[5]  = {50, 1024, 1024, 1024, 1024};
  const int Nd[5]  = {1024, 1024, 1024, 1024, 50};
  const int Kpd[5] = {64, 1024, 1024, 1024, 1024};
  const int Npd[5] = {1024, 1024, 1024, 1024, 64};
  for (int i = 0; i < 5; ++i) {
    int tot = Npd[i] * Kpd[i];
    prep_weight<<<dim3((tot + 255) / 256), 256, 0, stream>>>(
        Wp[i], bp[i], WT[i], bias[i], wtm[i], Kd[i], Nd[i], Kpd[i], Npd[i]);
  }

  init_y<<<dim3((M * 64 + 255) / 256), 256, 0, stream>>>(x, y, ybf, M);

  const float dtv = 1.0f / 32.0f;
  dim3 gL0(M / 128, 1024 / 128);        // 2048 blocks
  dim3 g256(M / 256 * (1024 / 256));    // 512 blocks, %8 == 0
  dim3 gL4(M / 64);                     // 512 blocks = 2/CU

  auto run_net = [&](float t, float ca, float cs, int mode) {
    gemm_bt<128,128,64,2,2,true,true><<<gL0, 256, 0, stream>>>(
        ybf, 64, WT[0], bias[0], wtm[0], t, act0, 1024, M, 64);
    gemm256<1024><<<g256, 512, 0, stream>>>(
        act0, WT[1], bias[1], wtm[1], t, act1, 1024, M, 1024);
    gemm256<1024><<<g256, 512, 0, stream>>>(
        act1, WT[2], bias[2], wtm[2], t, act0, 1024, M, 1024);
    gemm256<1024><<<g256, 512, 0, stream>>>(
        act0, WT[3], bias[3], wtm[3], t, act1, 1024, M, 1024);
    gemm_l4_rk4<<<gL4, 256, 0, stream>>>(
        act1, 1024, WT[4], bias[4], wtm[4], t,
        y, accb, ybf, ca, cs, mode, M, 1024);
  };

  for (int i = 0; i < 32; ++i) {
    const float t0 = i * dtv;
    const float tm = t0 + 0.5f * dtv;
    const float t1 = t0 + dtv;
    run_net(t0, 0.0f, 0.5f * dtv, 0);   // k1
    run_net(tm, 2.0f, 0.5f * dtv, 1);   // k2
    run_net(tm, 2.0f, dtv,        1);   // k3
    run_net(t1, 0.0f, dtv / 6.0f, 2);   // k4
  }

  extract_out<<<dim3((M * 3 + 255) / 256), 256, 0, stream>>>(y, (float*)d_out, M);
}